// Round 1
// 26503.806 us; speedup vs baseline: 1.2881x; 1.2881x over previous
//
#include <hip/hip_runtime.h>

// ---------------------------------------------------------------------------
// Graves handwriting synthesis: 3x peephole-LSTM(400) + soft window attention
// + MDN head.  B=32, T=400.  Persistent kernel, 2 grid barriers/step.
//
// Round 5 = round 4 structure, latency-hiding rework:
//  * Weights staged ONCE into LDS per block (8 cols x 2228 = 71KB, row
//    stride 2236 floats -> conflict-free ds_read_b128). No global WT, no
//    transpose phase, no per-step global weight stream.
//  * NTHR 512 -> 1024 (K quarters instead of halves): 16 waves/CU = 4/SIMD,
//    doubles latency hiding. Grid stays 201 blocks -> barrier cost unchanged.
//    __launch_bounds__(1024,4) caps VGPR at 128 -> residency guaranteed.
//  * All dot-product loads issued before finalize syncs; Q's two finalizes
//    (h2(t), h1(t+1)) merged into one LDS round-trip.
//  * Cross-block state scheme UNCHANGED from round 4 (verified): fp32
//    write-once rotating slots, relaxed agent-scope write-through stores,
//    relaxed-only two-level barrier with 32 flag lines, monotone epochs.
// ---------------------------------------------------------------------------

#define NBLK   201
#define NTHR   1024
#define TSTEPS 400
#define BATCH  32
#define UNITSN 400
#define NCHARS 73
#define UC     50
#define KTOT   2228   // 476 (z1) + 876 (z2) + 876 (z3)
#define WSTR   2236   // LDS weight row stride (floats); 2236%32=28 -> 8 cols
                      // hit 8 distinct bank quads -> conflict-free b128 reads
#define NGRP   8
#define NFLAG  32

typedef unsigned int       u32;
typedef unsigned long long u64;

// ---- ws byte layout ----
// [0,4096): barrier ints (memset to 0 each launch)
//   grp_cnt[g] at int g*16 (g<8); glob_cnt at int 128; flags[f] at int 256+f*16
#define STATE_BYTES 4096
#define HSLOT     12832                           // fp32 elems/slot (12800+32 pad)
#define H1_BYTE   4096
#define H2_BYTE   (H1_BYTE + TSTEPS * HSLOT * 4)
#define H3_BYTE   (H2_BYTE + TSTEPS * HSLOT * 4)
#define WSLOT     2368                            // fp32 elems/slot (2336+32 pad)
#define WH_BYTE   (H3_BYTE + TSTEPS * HSLOT * 4)
// end of ws usage: WH_BYTE + 400*WSLOT*4 = 65,386,496 bytes (~62 MB)

__device__ __forceinline__ float sigf(float x)   { return 1.0f / (1.0f + __expf(-x)); }
__device__ __forceinline__ float tanhf_(float x) { return 1.0f - 2.0f / (1.0f + __expf(2.0f * x)); }

// 100-float quarter dot: w from LDS (conflict-free), x from global (8 distinct
// b-rows per wave, 16B each). Full unroll -> loads issue early and deep.
__device__ __forceinline__ float dot100(const float* __restrict__ w,
                                        const float* __restrict__ x) {
  const float4* wv = (const float4*)w;
  const float4* xv = (const float4*)x;
  float s0 = 0.f, s1 = 0.f, s2 = 0.f, s3 = 0.f;
#pragma unroll
  for (int i = 0; i < 25; ++i) {
    float4 a = wv[i], bb = xv[i];
    s0 = fmaf(a.x, bb.x, s0); s1 = fmaf(a.y, bb.y, s1);
    s2 = fmaf(a.z, bb.z, s2); s3 = fmaf(a.w, bb.w, s3);
  }
  return (s0 + s1) + (s2 + s3);
}

// 73-float dot, K-quarter split {19,18,18,18}
__device__ __forceinline__ float dot73q(const float* __restrict__ w,
                                        const float* __restrict__ x, int kq) {
  int st = (kq == 0) ? 0 : 18 * kq + 1;
  int en = st + ((kq == 0) ? 19 : 18);
  float s = 0.f;
  for (int k = st; k < en; ++k) s = fmaf(w[k], x[k], s);
  return s;
}

extern "C" __global__ void __launch_bounds__(NTHR, 4)
hand_kernel(const float* __restrict__ xs, const int* __restrict__ chars,
            const int* __restrict__ lens,
            const float* __restrict__ Wx0, const float* __restrict__ Wh0,
            const float* __restrict__ b0, const float* __restrict__ p0,
            const float* __restrict__ Wx1, const float* __restrict__ Wh1,
            const float* __restrict__ b1, const float* __restrict__ p1,
            const float* __restrict__ Wx2, const float* __restrict__ Wh2,
            const float* __restrict__ b2, const float* __restrict__ p2,
            const float* __restrict__ Watt, const float* __restrict__ batt,
            const float* __restrict__ Wmdn, const float* __restrict__ bmdn,
            float* __restrict__ dout, char* __restrict__ wsb) {
  const int blk = blockIdx.x;
  const int tid = threadIdx.x;

  __shared__ __align__(16) float wlw[8 * WSTR];   // 71.6 KB weight tile
  __shared__ float zpart[NTHR], zpartB[NTHR];
  __shared__ float zbuf[256], zbufB[256];
  __shared__ float biasL[3][8];
  __shared__ float peepL[3][3][2];
  __shared__ float cstate[3][64];     // [layer][ul*32 + b]
  __shared__ int   bar_target;
  __shared__ float attacc[960];
  __shared__ float alphaL[320], betaL[320], kappaL[320];
  __shared__ float wlds[BATCH * NCHARS];

  int*   bar_i = (int*)wsb;
  float* h1h   = (float*)(wsb + H1_BYTE);
  float* h2h   = (float*)(wsb + H2_BYTE);
  float* h3h   = (float*)(wsb + H3_BYTE);
  float* whh   = (float*)(wsb + WH_BYTE);

  const int out = tid & 255;
  const int b   = out >> 3;    // batch 0..31
  const int c   = out & 7;     // col: (c>>2)=unit_local, (c&3)=gate (i,f,g,o)
  const int kq  = tid >> 8;    // k-quarter 0..3
  const int u0  = 2 * (blk - 1);

  if (tid == 0) bar_target = 0;
  if (tid < 192) cstate[tid / 64][tid % 64] = 0.f;
  if (tid < 320) kappaL[tid] = 0.f;

  // ---- one-time: stage this block's 8 weight columns into LDS ----
  if (blk > 0) {
    for (int idx = tid; idx < 8 * KTOT; idx += NTHR) {
      int cc = idx / KTOT, k = idx - cc * KTOT;
      int gcol = (cc & 3) * UNITSN + u0 + (cc >> 2);
      float v;
      if (k < 476)        v = (k < 76)  ? Wx0[(size_t)k * 1600 + gcol]
                                        : Wh0[(size_t)(k - 76) * 1600 + gcol];
      else if (k < 1352) { int q = k - 476;
                          v = (q < 476) ? Wx1[(size_t)q * 1600 + gcol]
                                        : Wh1[(size_t)(q - 476) * 1600 + gcol]; }
      else               { int q = k - 1352;
                          v = (q < 476) ? Wx2[(size_t)q * 1600 + gcol]
                                        : Wh2[(size_t)(q - 476) * 1600 + gcol]; }
      wlw[cc * WSTR + k] = v;
    }
    if (tid < 24) {
      int l = tid >> 3, cc = tid & 7;
      const float* bs = (l == 0) ? b0 : (l == 1) ? b1 : b2;
      biasL[l][cc] = bs[(cc & 3) * UNITSN + u0 + (cc >> 2)];
    }
    if (tid < 18) {
      int l = tid / 6, r = (tid % 6) >> 1, ul = tid & 1;
      const float* ps = (l == 0) ? p0 : (l == 1) ? p1 : p2;
      peepL[l][r][ul] = ps[r * UNITSN + u0 + ul];
    }
  }
  __syncthreads();

  const float* Wc = wlw + c * WSTR;   // this thread's column (LDS)

  // ---- relaxed-only two-level grid barrier (UNCHANGED from round 4) ----
  auto gridbar = [&]() {
    __syncthreads();
    if (tid == 0) {
      int e = ++bar_target;
      int g = blk & (NGRP - 1);
      int gsz = ((NBLK - 1 - g) >> 3) + 1;           // 26 for g=0, else 25
      int a = __hip_atomic_fetch_add(bar_i + g * 16, 1, __ATOMIC_RELAXED, __HIP_MEMORY_SCOPE_AGENT);
      if (a + 1 == e * gsz) {                        // last of my group this epoch
        int q = __hip_atomic_fetch_add(bar_i + 128, 1, __ATOMIC_RELAXED, __HIP_MEMORY_SCOPE_AGENT);
        if (((q + 1) & (NGRP - 1)) == 0) {           // last group: release all
          for (int f = 0; f < NFLAG; ++f)
            __hip_atomic_store(bar_i + 256 + f * 16, e, __ATOMIC_RELAXED, __HIP_MEMORY_SCOPE_AGENT);
        }
      }
      int* myflag = bar_i + 256 + (blk & (NFLAG - 1)) * 16;
      while (__hip_atomic_load(myflag, __ATOMIC_RELAXED, __HIP_MEMORY_SCOPE_AGENT) < e)
        __builtin_amdgcn_s_sleep(2);
    }
    __syncthreads();
  };

  // gate math for one layer, 2 units, one 8B write-through store
  auto gates = [&](int layer, const float* zb, int bb, float* hdst) {
    union { float f[2]; u64 v; } pk;
#pragma unroll
    for (int ul = 0; ul < 2; ++ul) {
      float zi = zb[bb * 8 + ul * 4 + 0], zf = zb[bb * 8 + ul * 4 + 1];
      float zg = zb[bb * 8 + ul * 4 + 2], zo = zb[bb * 8 + ul * 4 + 3];
      float cold = cstate[layer][ul * 32 + bb];
      float ig = sigf(zi + peepL[layer][0][ul] * cold);
      float fg = sigf(zf + peepL[layer][1][ul] * cold);
      float cn = fg * cold + ig * tanhf_(zg);
      float og = sigf(zo + peepL[layer][2][ul] * cn);
      cstate[layer][ul * 32 + bb] = cn;
      pk.f[ul] = og * tanhf_(cn);
    }
    __hip_atomic_store((u64*)(hdst + bb * UNITSN + u0), pk.v,
                       __ATOMIC_RELAXED, __HIP_MEMORY_SCOPE_AGENT);
  };

  // single-layer finalize: 4-partial LDS reduce + gates
  auto finalize1 = [&](int layer, float acc, float* hdst) {
    zpart[tid] = acc;
    __syncthreads();
    if (tid < 256)
      zbuf[tid] = zpart[tid] + zpart[tid + 256] + zpart[tid + 512] + zpart[tid + 768]
                + biasL[layer][tid & 7];
    __syncthreads();
    if (tid < 256 && (tid & 7) == 0) gates(layer, zbuf, tid >> 3, hdst);
    __syncthreads();
  };

  // merged Q finalize: h2(t) and (optionally) h1(t+1) in one LDS round-trip
  auto finalizeQ = [&](float a2v, float* h2dst, float a1v, float* h1dst, bool do1) {
    zpart[tid]  = a2v;
    zpartB[tid] = a1v;
    __syncthreads();
    if (tid < 256) {
      zbuf[tid]  = zpart[tid]  + zpart[tid + 256]  + zpart[tid + 512]  + zpart[tid + 768]
                 + biasL[1][tid & 7];
      zbufB[tid] = zpartB[tid] + zpartB[tid + 256] + zpartB[tid + 512] + zpartB[tid + 768]
                 + biasL[0][tid & 7];
    }
    __syncthreads();
    if (tid < 256 && (tid & 7) == 0) {
      gates(1, zbuf, tid >> 3, h2dst);
      if (do1) gates(0, zbufB, tid >> 3, h1dst);
    }
    __syncthreads();
  };

  auto attention = [&](const float* h1t, float* wdst) {
    for (int i = tid; i < 960; i += NTHR) attacc[i] = 0.f;
    __syncthreads();
    {
      // 1024 = 32 batches x 16 k-slices(25) x 2 j-halves(15)
      int ab = tid & 31, ks = (tid >> 5) & 15, jh = tid >> 9;
      float accs[15];
#pragma unroll
      for (int j = 0; j < 15; ++j) accs[j] = 0.f;
      const float* h1b = h1t + ab * UNITSN + ks * 25;
      const float* wr  = Watt + (ks * 25) * 30 + jh * 15;
      for (int kk = 0; kk < 25; ++kk) {
        float hv = h1b[kk];
#pragma unroll
        for (int j = 0; j < 15; ++j) accs[j] = fmaf(hv, wr[kk * 30 + j], accs[j]);
      }
#pragma unroll
      for (int j = 0; j < 15; ++j) atomicAdd(&attacc[ab * 30 + jh * 15 + j], accs[j]);
    }
    __syncthreads();
    if (tid < 320) {
      int bb = tid / 10, j = tid - bb * 10;
      float ah   = attacc[bb * 30 + j]      + batt[j];
      float bh   = attacc[bb * 30 + 10 + j] + batt[10 + j];
      float khat = attacc[bb * 30 + 20 + j] + batt[20 + j];
      float kap = kappaL[tid] + __expf(khat);
      kappaL[tid] = kap;
      alphaL[tid] = __expf(ah);
      betaL[tid]  = __expf(bh);
    }
    for (int i = tid; i < BATCH * NCHARS; i += NTHR) wlds[i] = 0.f;
    __syncthreads();
    for (int idx = tid; idx < BATCH * UC; idx += NTHR) {
      int bb = idx / UC, u = idx - bb * UC;
      if (u < lens[bb]) {
        float ph = 0.f;
#pragma unroll
        for (int j = 0; j < 10; ++j) {
          float d = kappaL[bb * 10 + j] - (float)u;
          ph = fmaf(alphaL[bb * 10 + j], __expf(-betaL[bb * 10 + j] * d * d), ph);
        }
        atomicAdd(&wlds[bb * NCHARS + chars[bb * UC + u]], ph);
      }
    }
    __syncthreads();
    for (int i = tid; i < (BATCH * NCHARS) / 2; i += NTHR) {
      union { float f[2]; u64 v; } pk;
      pk.f[0] = wlds[2 * i]; pk.f[1] = wlds[2 * i + 1];
      __hip_atomic_store((u64*)(wdst + 2 * i), pk.v,
                         __ATOMIC_RELAXED, __HIP_MEMORY_SCOPE_AGENT);
    }
  };

  // ---- prologue: h1(0) from x(0) only (h,c,w all zero) -> h1 slot 0 ----
  if (blk > 0) {
    float acc = 0.f;
    if (kq == 0) {
      const float* xr = xs + (b * TSTEPS + 0) * 3;
      acc = Wc[0] * xr[0] + Wc[1] * xr[1] + Wc[2] * xr[2];
    }
    finalize1(0, acc, h1h);
  }
  gridbar();

  float acc_z1 = 0.f, acc_z2 = 0.f, acc_z3 = 0.f;
  for (int t = 0; t < TSTEPS; ++t) {
    const float* h1t = h1h + (size_t)t * HSLOT + b * UNITSN;        // h1(t)
    const float* h2p = h2h + (size_t)(t - 1) * HSLOT + b * UNITSN;  // h2(t-1)
    const float* h3p = h3h + (size_t)(t - 1) * HSLOT + b * UNITSN;  // h3(t-1)
    const float* wrt = whh + (size_t)t * WSLOT + b * NCHARS;        // w(t)
    // ------------------------------ P(t) ------------------------------
    if (blk == 0) {
      attention(h1h + (size_t)t * HSLOT, whh + (size_t)t * WSLOT);
    } else {
      // all global h loads issue before any finalize sync
      float a3f = acc_z3;
      if (t > 0) a3f += dot100(Wc + 1428 + kq * 100, h2p + kq * 100);
      float a2 = dot100(Wc + 552 + kq * 100, h1t + kq * 100);
      if (t > 0) a2 += dot100(Wc + 952 + kq * 100, h2p + kq * 100);
      float a1 = 0.f;
      if (t < TSTEPS - 1) a1 = dot100(Wc + 76 + kq * 100, h1t + kq * 100);
      if (kq == 0) {
        const float* xr = xs + (b * TSTEPS + t) * 3;
        a2 += Wc[476] * xr[0] + Wc[477] * xr[1] + Wc[478] * xr[2];
        if (t < TSTEPS - 1) {
          const float* x1 = xr + 3;
          a1 += Wc[0] * x1[0] + Wc[1] * x1[1] + Wc[2] * x1[2];
        }
      }
      if (t > 0) finalize1(2, a3f, h3h + (size_t)(t - 1) * HSLOT);  // h3(t-1)
      acc_z2 = a2;
      acc_z1 = a1;
    }
    gridbar();
    // ------------------------------ Q(t) ------------------------------
    if (blk > 0) {
      bool do1 = (t < TSTEPS - 1);
      float q2 = acc_z2 + dot73q(Wc + 479, wrt, kq);
      float q1 = 0.f;
      if (do1) q1 = acc_z1 + dot73q(Wc + 3, wrt, kq);
      float a3 = dot73q(Wc + 1355, wrt, kq);
      if (t > 0) a3 += dot100(Wc + 1828 + kq * 100, h3p + kq * 100);
      if (kq == 0) {
        const float* xr = xs + (b * TSTEPS + t) * 3;
        a3 += Wc[1352] * xr[0] + Wc[1353] * xr[1] + Wc[1354] * xr[2];
      }
      finalizeQ(q2, h2h + (size_t)t * HSLOT,
                q1, h1h + (size_t)(t + 1) * HSLOT, do1);
      acc_z3 = a3;
    }
    gridbar();
  }
  // ---- epilogue step: finish z3(T-1) -> h3 slot T-1 ----
  if (blk > 0) {
    const float* h2l = h2h + (size_t)(TSTEPS - 1) * HSLOT + b * UNITSN;
    float a3 = acc_z3 + dot100(Wc + 1428 + kq * 100, h2l + kq * 100);
    finalize1(2, a3, h3h + (size_t)(TSTEPS - 1) * HSLOT);
  }
  gridbar();

  // ---- MDN head + output transforms (parallel over 12800 (b,t) rows) ----
  {
    int j = tid & 127, ks = tid >> 7;   // 8 k-slices of 50
    for (int i0 = 0; i0 < 64; i0 += 4) {
      float acc[4] = {0.f, 0.f, 0.f, 0.f};
      const float* hp[4];
      bool val[4];
      for (int r = 0; r < 4; ++r) {
        int row = blk + (i0 + r) * NBLK;
        val[r] = (row < 12800);
        hp[r] = val[r] ? (h3h + (size_t)(row % TSTEPS) * HSLOT + (row / TSTEPS) * UNITSN + ks * 50)
                       : h3h;
      }
      if (j < 121) {
        const float* wp = Wmdn + (size_t)(ks * 50) * 121 + j;
        for (int k = 0; k < 50; ++k) {
          float wv = wp[(size_t)k * 121];
#pragma unroll
          for (int r = 0; r < 4; ++r) acc[r] = fmaf(hp[r][k], wv, acc[r]);
        }
      }
      for (int r = 0; r < 4; ++r) {
        zpart[tid] = acc[r];
        __syncthreads();
        if (tid < 121) {
          float s = bmdn[tid];
#pragma unroll
          for (int m = 0; m < 8; ++m) s += zpart[tid + m * 128];
          zbuf[tid] = s;
        }
        __syncthreads();
        if (tid == 0) {
          float mx = zbuf[0];
          for (int q = 1; q < 20; ++q) mx = fmaxf(mx, zbuf[q]);
          float s = 0.f;
          for (int q = 0; q < 20; ++q) s += __expf(zbuf[q] - mx);
          zbuf[126] = mx;
          zbuf[127] = 1.f / s;
        }
        __syncthreads();
        if (val[r] && tid < 121) {
          int row = blk + (i0 + r) * NBLK;
          float y = zbuf[tid], o;
          if (tid < 20)       o = __expf(y - zbuf[126]) * zbuf[127];  // softmax(pi)
          else if (tid < 60)  o = y;                                   // mu1, mu2
          else if (tid < 100) o = __expf(y);                           // s1, s2
          else if (tid < 120) o = tanhf_(y);                           // rho
          else                o = sigf(y);                             // eos
          dout[(size_t)row * 121 + tid] = o;
        }
        __syncthreads();
      }
    }
  }
}

extern "C" void kernel_launch(void* const* d_in, const int* in_sizes, int n_in,
                              void* d_out, int out_size, void* d_ws, size_t ws_size,
                              hipStream_t stream) {
  const float* xs   = (const float*)d_in[0];
  const int*   chrs = (const int*)d_in[1];
  const int*   lens = (const int*)d_in[2];
  const float* Wx0  = (const float*)d_in[3];
  const float* Wh0  = (const float*)d_in[4];
  const float* b0   = (const float*)d_in[5];
  const float* p0   = (const float*)d_in[6];
  const float* Wx1  = (const float*)d_in[7];
  const float* Wh1  = (const float*)d_in[8];
  const float* b1   = (const float*)d_in[9];
  const float* p1   = (const float*)d_in[10];
  const float* Wx2  = (const float*)d_in[11];
  const float* Wh2  = (const float*)d_in[12];
  const float* b2   = (const float*)d_in[13];
  const float* p2   = (const float*)d_in[14];
  const float* Watt = (const float*)d_in[15];
  const float* batt = (const float*)d_in[16];
  const float* Wmdn = (const float*)d_in[17];
  const float* bmdn = (const float*)d_in[18];

  // zero barrier counters/flags only (4KB); everything else is write-once
  hipMemsetAsync(d_ws, 0, STATE_BYTES, stream);
  hipLaunchKernelGGL(hand_kernel, dim3(NBLK), dim3(NTHR), 0, stream,
                     xs, chrs, lens, Wx0, Wh0, b0, p0, Wx1, Wh1, b1, p1,
                     Wx2, Wh2, b2, p2, Watt, batt, Wmdn, bmdn,
                     (float*)d_out, (char*)d_ws);
}

// Round 2
// 17696.541 us; speedup vs baseline: 1.9292x; 1.4977x over previous
//
#include <hip/hip_runtime.h>

// ---------------------------------------------------------------------------
// Graves handwriting synthesis: 3x peephole-LSTM(400) + soft window attention
// + MDN head.  B=32, T=400.  Persistent kernel, 2 grid barriers/step.
//
// Round 6 = round 5 structure, spill elimination:
//  * Round 5 counters showed 74.5 GB deterministic HBM traffic (vs 0.6 GB in
//    round 4) with VGPR_Count=64: the allocator squeezed for 8 waves/EU that
//    the 99KB LDS makes unreachable (1 block/CU = 4 waves/EU) and spilled the
//    unrolled dot windows to scratch every step.
//  * Fix: amdgpu_waves_per_eu(4,4) pins the occupancy target -> 128 VGPR
//    budget; dual-dot fusion (two weight streams per x stream) + unroll 5
//    shrinks the live window structurally.
//  * Weights in LDS (71KB, stride 2236 -> conflict-free), NTHR=1024,
//    cross-block state scheme UNCHANGED from round 4/5 (verified): fp32
//    write-once rotating slots, relaxed agent-scope write-through stores,
//    relaxed-only two-level barrier with 32 flag lines, monotone epochs.
// ---------------------------------------------------------------------------

#define NBLK   201
#define NTHR   1024
#define TSTEPS 400
#define BATCH  32
#define UNITSN 400
#define NCHARS 73
#define UC     50
#define KTOT   2228   // 476 (z1) + 876 (z2) + 876 (z3)
#define WSTR   2236   // LDS weight row stride (floats); 2236%32=28 -> 8 cols
                      // hit 8 distinct bank quads -> conflict-free b128 reads
#define NGRP   8
#define NFLAG  32

typedef unsigned int       u32;
typedef unsigned long long u64;

// ---- ws byte layout ----
// [0,4096): barrier ints (memset to 0 each launch)
//   grp_cnt[g] at int g*16 (g<8); glob_cnt at int 128; flags[f] at int 256+f*16
#define STATE_BYTES 4096
#define HSLOT     12832                           // fp32 elems/slot (12800+32 pad)
#define H1_BYTE   4096
#define H2_BYTE   (H1_BYTE + TSTEPS * HSLOT * 4)
#define H3_BYTE   (H2_BYTE + TSTEPS * HSLOT * 4)
#define WSLOT     2368                            // fp32 elems/slot (2336+32 pad)
#define WH_BYTE   (H3_BYTE + TSTEPS * HSLOT * 4)
// end of ws usage: WH_BYTE + 400*WSLOT*4 = 65,386,496 bytes (~62 MB)

__device__ __forceinline__ float sigf(float x)   { return 1.0f / (1.0f + __expf(-x)); }
__device__ __forceinline__ float tanhf_(float x) { return 1.0f - 2.0f / (1.0f + __expf(2.0f * x)); }

// single 100-float quarter dot: w from LDS, x from global
__device__ __forceinline__ float dot100(const float* __restrict__ w,
                                        const float* __restrict__ x) {
  const float4* wv = (const float4*)w;
  const float4* xv = (const float4*)x;
  float s0 = 0.f, s1 = 0.f, s2 = 0.f, s3 = 0.f;
#pragma unroll 5
  for (int i = 0; i < 25; ++i) {
    float4 a = wv[i], bb = xv[i];
    s0 = fmaf(a.x, bb.x, s0); s1 = fmaf(a.y, bb.y, s1);
    s2 = fmaf(a.z, bb.z, s2); s3 = fmaf(a.w, bb.w, s3);
  }
  return (s0 + s1) + (s2 + s3);
}

// dual dot sharing one x stream: ra += wa.x, rb += wb.x (halves global loads)
__device__ __forceinline__ void dot100x2(const float* __restrict__ wa,
                                         const float* __restrict__ wb,
                                         const float* __restrict__ x,
                                         float& ra, float& rb) {
  const float4* av = (const float4*)wa;
  const float4* bv = (const float4*)wb;
  const float4* xv = (const float4*)x;
  float a0 = 0.f, a1 = 0.f, a2 = 0.f, a3 = 0.f;
  float c0 = 0.f, c1 = 0.f, c2 = 0.f, c3 = 0.f;
#pragma unroll 5
  for (int i = 0; i < 25; ++i) {
    float4 xx = xv[i], aa = av[i], bb = bv[i];
    a0 = fmaf(aa.x, xx.x, a0); a1 = fmaf(aa.y, xx.y, a1);
    a2 = fmaf(aa.z, xx.z, a2); a3 = fmaf(aa.w, xx.w, a3);
    c0 = fmaf(bb.x, xx.x, c0); c1 = fmaf(bb.y, xx.y, c1);
    c2 = fmaf(bb.z, xx.z, c2); c3 = fmaf(bb.w, xx.w, c3);
  }
  ra += (a0 + a1) + (a2 + a3);
  rb += (c0 + c1) + (c2 + c3);
}

// triple 73-float dot sharing one x stream, K-quarter split {19,18,18,18}
__device__ __forceinline__ void dot73x3(const float* __restrict__ w1,
                                        const float* __restrict__ w2,
                                        const float* __restrict__ w3,
                                        const float* __restrict__ x, int kq,
                                        float& r1, float& r2, float& r3) {
  int st = (kq == 0) ? 0 : 18 * kq + 1;
  int en = st + ((kq == 0) ? 19 : 18);
  float s1 = 0.f, s2 = 0.f, s3 = 0.f;
  for (int k = st; k < en; ++k) {
    float xv = x[k];
    s1 = fmaf(w1[k], xv, s1); s2 = fmaf(w2[k], xv, s2); s3 = fmaf(w3[k], xv, s3);
  }
  r1 += s1; r2 += s2; r3 += s3;
}

extern "C" __global__ void __launch_bounds__(NTHR)
__attribute__((amdgpu_waves_per_eu(4, 4)))
hand_kernel(const float* __restrict__ xs, const int* __restrict__ chars,
            const int* __restrict__ lens,
            const float* __restrict__ Wx0, const float* __restrict__ Wh0,
            const float* __restrict__ b0, const float* __restrict__ p0,
            const float* __restrict__ Wx1, const float* __restrict__ Wh1,
            const float* __restrict__ b1, const float* __restrict__ p1,
            const float* __restrict__ Wx2, const float* __restrict__ Wh2,
            const float* __restrict__ b2, const float* __restrict__ p2,
            const float* __restrict__ Watt, const float* __restrict__ batt,
            const float* __restrict__ Wmdn, const float* __restrict__ bmdn,
            float* __restrict__ dout, char* __restrict__ wsb) {
  const int blk = blockIdx.x;
  const int tid = threadIdx.x;

  __shared__ __align__(16) float wlw[8 * WSTR];   // 71.6 KB weight tile
  __shared__ float zpart[NTHR], zpartB[NTHR];
  __shared__ float zbuf[256], zbufB[256];
  __shared__ float biasL[3][8];
  __shared__ float peepL[3][3][2];
  __shared__ float cstate[3][64];     // [layer][ul*32 + b]
  __shared__ int   bar_target;
  __shared__ float attacc[960];
  __shared__ float alphaL[320], betaL[320], kappaL[320];
  __shared__ float wlds[BATCH * NCHARS];

  int*   bar_i = (int*)wsb;
  float* h1h   = (float*)(wsb + H1_BYTE);
  float* h2h   = (float*)(wsb + H2_BYTE);
  float* h3h   = (float*)(wsb + H3_BYTE);
  float* whh   = (float*)(wsb + WH_BYTE);

  const int out = tid & 255;
  const int b   = out >> 3;    // batch 0..31
  const int c   = out & 7;     // col: (c>>2)=unit_local, (c&3)=gate (i,f,g,o)
  const int kq  = tid >> 8;    // k-quarter 0..3
  const int u0  = 2 * (blk - 1);

  if (tid == 0) bar_target = 0;
  if (tid < 192) cstate[tid / 64][tid % 64] = 0.f;
  if (tid < 320) kappaL[tid] = 0.f;

  // ---- one-time: stage this block's 8 weight columns into LDS ----
  if (blk > 0) {
    for (int idx = tid; idx < 8 * KTOT; idx += NTHR) {
      int cc = idx / KTOT, k = idx - cc * KTOT;
      int gcol = (cc & 3) * UNITSN + u0 + (cc >> 2);
      float v;
      if (k < 476)        v = (k < 76)  ? Wx0[(size_t)k * 1600 + gcol]
                                        : Wh0[(size_t)(k - 76) * 1600 + gcol];
      else if (k < 1352) { int q = k - 476;
                          v = (q < 476) ? Wx1[(size_t)q * 1600 + gcol]
                                        : Wh1[(size_t)(q - 476) * 1600 + gcol]; }
      else               { int q = k - 1352;
                          v = (q < 476) ? Wx2[(size_t)q * 1600 + gcol]
                                        : Wh2[(size_t)(q - 476) * 1600 + gcol]; }
      wlw[cc * WSTR + k] = v;
    }
    if (tid < 24) {
      int l = tid >> 3, cc = tid & 7;
      const float* bs = (l == 0) ? b0 : (l == 1) ? b1 : b2;
      biasL[l][cc] = bs[(cc & 3) * UNITSN + u0 + (cc >> 2)];
    }
    if (tid < 18) {
      int l = tid / 6, r = (tid % 6) >> 1, ul = tid & 1;
      const float* ps = (l == 0) ? p0 : (l == 1) ? p1 : p2;
      peepL[l][r][ul] = ps[r * UNITSN + u0 + ul];
    }
  }
  __syncthreads();

  const float* Wc = wlw + c * WSTR;   // this thread's column (LDS)

  // ---- relaxed-only two-level grid barrier (UNCHANGED, verified) ----
  auto gridbar = [&]() {
    __syncthreads();
    if (tid == 0) {
      int e = ++bar_target;
      int g = blk & (NGRP - 1);
      int gsz = ((NBLK - 1 - g) >> 3) + 1;           // 26 for g=0, else 25
      int a = __hip_atomic_fetch_add(bar_i + g * 16, 1, __ATOMIC_RELAXED, __HIP_MEMORY_SCOPE_AGENT);
      if (a + 1 == e * gsz) {                        // last of my group this epoch
        int q = __hip_atomic_fetch_add(bar_i + 128, 1, __ATOMIC_RELAXED, __HIP_MEMORY_SCOPE_AGENT);
        if (((q + 1) & (NGRP - 1)) == 0) {           // last group: release all
          for (int f = 0; f < NFLAG; ++f)
            __hip_atomic_store(bar_i + 256 + f * 16, e, __ATOMIC_RELAXED, __HIP_MEMORY_SCOPE_AGENT);
        }
      }
      int* myflag = bar_i + 256 + (blk & (NFLAG - 1)) * 16;
      while (__hip_atomic_load(myflag, __ATOMIC_RELAXED, __HIP_MEMORY_SCOPE_AGENT) < e)
        __builtin_amdgcn_s_sleep(2);
    }
    __syncthreads();
  };

  // gate math for one layer, 2 units, one 8B write-through store
  auto gates = [&](int layer, const float* zb, int bb, float* hdst) {
    union { float f[2]; u64 v; } pk;
#pragma unroll
    for (int ul = 0; ul < 2; ++ul) {
      float zi = zb[bb * 8 + ul * 4 + 0], zf = zb[bb * 8 + ul * 4 + 1];
      float zg = zb[bb * 8 + ul * 4 + 2], zo = zb[bb * 8 + ul * 4 + 3];
      float cold = cstate[layer][ul * 32 + bb];
      float ig = sigf(zi + peepL[layer][0][ul] * cold);
      float fg = sigf(zf + peepL[layer][1][ul] * cold);
      float cn = fg * cold + ig * tanhf_(zg);
      float og = sigf(zo + peepL[layer][2][ul] * cn);
      cstate[layer][ul * 32 + bb] = cn;
      pk.f[ul] = og * tanhf_(cn);
    }
    __hip_atomic_store((u64*)(hdst + bb * UNITSN + u0), pk.v,
                       __ATOMIC_RELAXED, __HIP_MEMORY_SCOPE_AGENT);
  };

  // single-layer finalize: 4-partial LDS reduce + gates
  auto finalize1 = [&](int layer, float acc, float* hdst) {
    zpart[tid] = acc;
    __syncthreads();
    if (tid < 256)
      zbuf[tid] = zpart[tid] + zpart[tid + 256] + zpart[tid + 512] + zpart[tid + 768]
                + biasL[layer][tid & 7];
    __syncthreads();
    if (tid < 256 && (tid & 7) == 0) gates(layer, zbuf, tid >> 3, hdst);
    __syncthreads();
  };

  // merged Q finalize: h2(t) and (optionally) h1(t+1) in one LDS round-trip
  auto finalizeQ = [&](float a2v, float* h2dst, float a1v, float* h1dst, bool do1) {
    zpart[tid]  = a2v;
    zpartB[tid] = a1v;
    __syncthreads();
    if (tid < 256) {
      zbuf[tid]  = zpart[tid]  + zpart[tid + 256]  + zpart[tid + 512]  + zpart[tid + 768]
                 + biasL[1][tid & 7];
      zbufB[tid] = zpartB[tid] + zpartB[tid + 256] + zpartB[tid + 512] + zpartB[tid + 768]
                 + biasL[0][tid & 7];
    }
    __syncthreads();
    if (tid < 256 && (tid & 7) == 0) {
      gates(1, zbuf, tid >> 3, h2dst);
      if (do1) gates(0, zbufB, tid >> 3, h1dst);
    }
    __syncthreads();
  };

  auto attention = [&](const float* h1t, float* wdst) {
    for (int i = tid; i < 960; i += NTHR) attacc[i] = 0.f;
    __syncthreads();
    {
      // 1024 = 32 batches x 16 k-slices(25) x 2 j-halves(15)
      int ab = tid & 31, ks = (tid >> 5) & 15, jh = tid >> 9;
      float accs[15];
#pragma unroll
      for (int j = 0; j < 15; ++j) accs[j] = 0.f;
      const float* h1b = h1t + ab * UNITSN + ks * 25;
      const float* wr  = Watt + (ks * 25) * 30 + jh * 15;
      for (int kk = 0; kk < 25; ++kk) {
        float hv = h1b[kk];
#pragma unroll
        for (int j = 0; j < 15; ++j) accs[j] = fmaf(hv, wr[kk * 30 + j], accs[j]);
      }
#pragma unroll
      for (int j = 0; j < 15; ++j) atomicAdd(&attacc[ab * 30 + jh * 15 + j], accs[j]);
    }
    __syncthreads();
    if (tid < 320) {
      int bb = tid / 10, j = tid - bb * 10;
      float ah   = attacc[bb * 30 + j]      + batt[j];
      float bh   = attacc[bb * 30 + 10 + j] + batt[10 + j];
      float khat = attacc[bb * 30 + 20 + j] + batt[20 + j];
      float kap = kappaL[tid] + __expf(khat);
      kappaL[tid] = kap;
      alphaL[tid] = __expf(ah);
      betaL[tid]  = __expf(bh);
    }
    for (int i = tid; i < BATCH * NCHARS; i += NTHR) wlds[i] = 0.f;
    __syncthreads();
    for (int idx = tid; idx < BATCH * UC; idx += NTHR) {
      int bb = idx / UC, u = idx - bb * UC;
      if (u < lens[bb]) {
        float ph = 0.f;
#pragma unroll
        for (int j = 0; j < 10; ++j) {
          float d = kappaL[bb * 10 + j] - (float)u;
          ph = fmaf(alphaL[bb * 10 + j], __expf(-betaL[bb * 10 + j] * d * d), ph);
        }
        atomicAdd(&wlds[bb * NCHARS + chars[bb * UC + u]], ph);
      }
    }
    __syncthreads();
    for (int i = tid; i < (BATCH * NCHARS) / 2; i += NTHR) {
      union { float f[2]; u64 v; } pk;
      pk.f[0] = wlds[2 * i]; pk.f[1] = wlds[2 * i + 1];
      __hip_atomic_store((u64*)(wdst + 2 * i), pk.v,
                         __ATOMIC_RELAXED, __HIP_MEMORY_SCOPE_AGENT);
    }
  };

  // ---- prologue: h1(0) from x(0) only (h,c,w all zero) -> h1 slot 0 ----
  if (blk > 0) {
    float acc = 0.f;
    if (kq == 0) {
      const float* xr = xs + (b * TSTEPS + 0) * 3;
      acc = Wc[0] * xr[0] + Wc[1] * xr[1] + Wc[2] * xr[2];
    }
    finalize1(0, acc, h1h);
  }
  gridbar();

  float acc_z1 = 0.f, acc_z2 = 0.f, acc_z3 = 0.f;
  for (int t = 0; t < TSTEPS; ++t) {
    const float* h1t = h1h + (size_t)t * HSLOT + b * UNITSN;        // h1(t)
    const float* h2p = h2h + (size_t)(t - 1) * HSLOT + b * UNITSN;  // h2(t-1)
    const float* h3p = h3h + (size_t)(t - 1) * HSLOT + b * UNITSN;  // h3(t-1)
    const float* wrt = whh + (size_t)t * WSLOT + b * NCHARS;        // w(t)
    // ------------------------------ P(t) ------------------------------
    if (blk == 0) {
      attention(h1h + (size_t)t * HSLOT, whh + (size_t)t * WSLOT);
    } else {
      // dual dots: one x stream feeds two weight streams
      float a3f = acc_z3, a2 = 0.f, a1 = 0.f;
      if (t > 0)
        dot100x2(Wc + 1428 + kq * 100, Wc + 952 + kq * 100, h2p + kq * 100, a3f, a2);
      dot100x2(Wc + 552 + kq * 100, Wc + 76 + kq * 100, h1t + kq * 100, a2, a1);
      if (kq == 0) {
        const float* xr = xs + (b * TSTEPS + t) * 3;
        a2 += Wc[476] * xr[0] + Wc[477] * xr[1] + Wc[478] * xr[2];
        if (t < TSTEPS - 1) {
          const float* x1 = xr + 3;
          a1 += Wc[0] * x1[0] + Wc[1] * x1[1] + Wc[2] * x1[2];
        }
      }
      if (t > 0) finalize1(2, a3f, h3h + (size_t)(t - 1) * HSLOT);  // h3(t-1)
      acc_z2 = a2;
      acc_z1 = a1;
    }
    gridbar();
    // ------------------------------ Q(t) ------------------------------
    if (blk > 0) {
      bool do1 = (t < TSTEPS - 1);
      float q2 = acc_z2, q1 = acc_z1, a3 = 0.f;
      dot73x3(Wc + 479, Wc + 3, Wc + 1355, wrt, kq, q2, q1, a3);
      if (t > 0) a3 += dot100(Wc + 1828 + kq * 100, h3p + kq * 100);
      if (kq == 0) {
        const float* xr = xs + (b * TSTEPS + t) * 3;
        a3 += Wc[1352] * xr[0] + Wc[1353] * xr[1] + Wc[1354] * xr[2];
      }
      finalizeQ(q2, h2h + (size_t)t * HSLOT,
                q1, h1h + (size_t)(t + 1) * HSLOT, do1);
      acc_z3 = a3;
    }
    gridbar();
  }
  // ---- epilogue step: finish z3(T-1) -> h3 slot T-1 ----
  if (blk > 0) {
    const float* h2l = h2h + (size_t)(TSTEPS - 1) * HSLOT + b * UNITSN;
    float a3 = acc_z3 + dot100(Wc + 1428 + kq * 100, h2l + kq * 100);
    finalize1(2, a3, h3h + (size_t)(TSTEPS - 1) * HSLOT);
  }
  gridbar();

  // ---- MDN head + output transforms (parallel over 12800 (b,t) rows) ----
  {
    int j = tid & 127, ks = tid >> 7;   // 8 k-slices of 50
    for (int i0 = 0; i0 < 64; i0 += 4) {
      float acc[4] = {0.f, 0.f, 0.f, 0.f};
      const float* hp[4];
      bool val[4];
      for (int r = 0; r < 4; ++r) {
        int row = blk + (i0 + r) * NBLK;
        val[r] = (row < 12800);
        hp[r] = val[r] ? (h3h + (size_t)(row % TSTEPS) * HSLOT + (row / TSTEPS) * UNITSN + ks * 50)
                       : h3h;
      }
      if (j < 121) {
        const float* wp = Wmdn + (size_t)(ks * 50) * 121 + j;
        for (int k = 0; k < 50; ++k) {
          float wv = wp[(size_t)k * 121];
#pragma unroll
          for (int r = 0; r < 4; ++r) acc[r] = fmaf(hp[r][k], wv, acc[r]);
        }
      }
      for (int r = 0; r < 4; ++r) {
        zpart[tid] = acc[r];
        __syncthreads();
        if (tid < 121) {
          float s = bmdn[tid];
#pragma unroll
          for (int m = 0; m < 8; ++m) s += zpart[tid + m * 128];
          zbuf[tid] = s;
        }
        __syncthreads();
        if (tid == 0) {
          float mx = zbuf[0];
          for (int q = 1; q < 20; ++q) mx = fmaxf(mx, zbuf[q]);
          float s = 0.f;
          for (int q = 0; q < 20; ++q) s += __expf(zbuf[q] - mx);
          zbuf[126] = mx;
          zbuf[127] = 1.f / s;
        }
        __syncthreads();
        if (val[r] && tid < 121) {
          int row = blk + (i0 + r) * NBLK;
          float y = zbuf[tid], o;
          if (tid < 20)       o = __expf(y - zbuf[126]) * zbuf[127];  // softmax(pi)
          else if (tid < 60)  o = y;                                   // mu1, mu2
          else if (tid < 100) o = __expf(y);                           // s1, s2
          else if (tid < 120) o = tanhf_(y);                           // rho
          else                o = sigf(y);                             // eos
          dout[(size_t)row * 121 + tid] = o;
        }
        __syncthreads();
      }
    }
  }
}

extern "C" void kernel_launch(void* const* d_in, const int* in_sizes, int n_in,
                              void* d_out, int out_size, void* d_ws, size_t ws_size,
                              hipStream_t stream) {
  const float* xs   = (const float*)d_in[0];
  const int*   chrs = (const int*)d_in[1];
  const int*   lens = (const int*)d_in[2];
  const float* Wx0  = (const float*)d_in[3];
  const float* Wh0  = (const float*)d_in[4];
  const float* b0   = (const float*)d_in[5];
  const float* p0   = (const float*)d_in[6];
  const float* Wx1  = (const float*)d_in[7];
  const float* Wh1  = (const float*)d_in[8];
  const float* b1   = (const float*)d_in[9];
  const float* p1   = (const float*)d_in[10];
  const float* Wx2  = (const float*)d_in[11];
  const float* Wh2  = (const float*)d_in[12];
  const float* b2   = (const float*)d_in[13];
  const float* p2   = (const float*)d_in[14];
  const float* Watt = (const float*)d_in[15];
  const float* batt = (const float*)d_in[16];
  const float* Wmdn = (const float*)d_in[17];
  const float* bmdn = (const float*)d_in[18];

  // zero barrier counters/flags only (4KB); everything else is write-once
  hipMemsetAsync(d_ws, 0, STATE_BYTES, stream);
  hipLaunchKernelGGL(hand_kernel, dim3(NBLK), dim3(NTHR), 0, stream,
                     xs, chrs, lens, Wx0, Wh0, b0, p0, Wx1, Wh1, b1, p1,
                     Wx2, Wh2, b2, p2, Watt, batt, Wmdn, bmdn,
                     (float*)d_out, (char*)d_ws);
}